// Round 7
// baseline (499.322 us; speedup 1.0000x reference)
//
#include <hip/hip_runtime.h>
#include <hip/hip_bf16.h>
#include <hip/hip_fp16.h>

#define N_NODES 100000
#define N_EDGES 800000
#define N_GRAPHS 512
#define D 128
#define EPSV 1e-5f

// radix-bucket CSR build params (256-node buckets)
#define NBLK 256
#define EPB  3125
#define NBUK 391          // ceil(100000/256)
#define MAXB 3072

// MFMA GEMM LDS layout (dwords): Ah 64 rows x 68dw, Wt2 128 cols x 68dw
#define LSTR 68
#define WOFF 4352

#define NSLOT 64          // stats scatter slots

// slice-partitioned gather table: [8 slices][N_NODES][16 halves]
#define NSLICE 8
#define CHUNK 512         // nodes per k_agg block
#define NCHUNK 196        // ceil(100000/512)

typedef _Float16 half8 __attribute__((ext_vector_type(8)));
typedef float floatx16 __attribute__((ext_vector_type(16)));

__device__ __forceinline__ float relu_f(float x){ return fmaxf(x, 0.0f); }

// inclusive scan of sd[0..511] with 256 threads
__device__ __forceinline__ void scan512(int* sd, int t)
{
    for (int off = 1; off < 512; off <<= 1){
        int i2 = t + 256;
        int v1 = (t  >= off) ? sd[t  - off] : 0;
        int v2 = (i2 >= off) ? sd[i2 - off] : 0;
        __syncthreads();
        sd[t]  += v1;
        sd[i2] += v2;
        __syncthreads();
    }
}

// ---------------- FRONT: p1 histogram (blocks 0..255) | wprep+zero+gstart ------
__global__ __launch_bounds__(256) void k_front(const int* __restrict__ dst,
                                               int* __restrict__ blockHist,
                                               const float* __restrict__ Ws,
                                               unsigned int* __restrict__ wpack,
                                               unsigned int* __restrict__ zbase,
                                               int zn,
                                               const int* __restrict__ batch,
                                               int* __restrict__ gstart,
                                               int* __restrict__ row_ptr)
{
    __shared__ int h[NBUK];
    int j = blockIdx.x, t = threadIdx.x;
    if (j < NBLK){
        for (int u = t; u < NBUK; u += 256) h[u] = 0;
        __syncthreads();
        int e0 = j * EPB;
        for (int e = e0 + t; e < e0 + EPB; e += 256)
            atomicAdd(&h[dst[e] >> 8], 1);
        __syncthreads();
        for (int u = t; u < NBUK; u += 256) blockHist[j * NBUK + u] = h[u];
    } else {
        int b = j - NBLK;                 // 0..95
        int idx = b * 256 + t;
        if (idx == 0){
            row_ptr[N_NODES] = N_EDGES;
            gstart[N_GRAPHS] = N_NODES;
        }
        if (idx < 3 * 128 * 64){
            int l  = idx >> 13;
            int r  = idx & 8191;
            int c  = r >> 6;
            int k2 = r & 63;
            const float* W = Ws + l * D * D;
            __half2 hh = __floats2half2_rn(W[(size_t)(2 * k2) * D + c],
                                           W[(size_t)(2 * k2 + 1) * D + c]);
            wpack[idx] = *(unsigned int*)&hh;
        }
        int stride = 96 * 256;
        for (int i = idx; i < zn; i += stride) zbase[i] = 0u;
        if (idx < N_GRAPHS){
            int g = idx;
            int lo = 0, hi = N_NODES;
            while (lo < hi){ int m = (lo + hi) >> 1; if (batch[m] < g) lo = m + 1; else hi = m; }
            gstart[g] = lo;
        }
    }
}

// ---------------- P2a: per-bucket column scan (NBUK blocks, parallel) ----------
__global__ __launch_bounds__(256) void k_p2a(const int* __restrict__ blockHist,
                                             int* __restrict__ colScan,
                                             int* __restrict__ bucketTotal)
{
    __shared__ int sd[256];
    int b = blockIdx.x, t = threadIdx.x;
    int v = blockHist[t * NBUK + b];
    sd[t] = v;
    __syncthreads();
    for (int off = 1; off < 256; off <<= 1){
        int u = (t >= off) ? sd[t - off] : 0;
        __syncthreads();
        sd[t] += u;
        __syncthreads();
    }
    colScan[t * NBUK + b] = sd[t] - v;
    if (t == 255) bucketTotal[b] = sd[255];
}

// ---------------- P3: scatter edges into bucket-sorted ebuf (LDS cursors) ------
__global__ __launch_bounds__(256) void k_p3(const int* __restrict__ src,
                                            const int* __restrict__ dst,
                                            const int* __restrict__ colScan,
                                            const int* __restrict__ bucketTotal,
                                            int2* __restrict__ ebuf)
{
    __shared__ int sd[512];
    __shared__ int cur[NBUK];
    int j = blockIdx.x, t = threadIdx.x;
    int i2 = t + 256;
    sd[t]  = (t  < NBUK) ? bucketTotal[t]  : 0;
    sd[i2] = (i2 < NBUK) ? bucketTotal[i2] : 0;
    __syncthreads();
    scan512(sd, t);
    if (t < NBUK)
        cur[t]  = (sd[t]  - bucketTotal[t])  + colScan[j * NBUK + t];
    if (i2 < NBUK)
        cur[i2] = (sd[i2] - bucketTotal[i2]) + colScan[j * NBUK + i2];
    __syncthreads();
    int e0 = j * EPB;
    for (int e = e0 + t; e < e0 + EPB; e += 256){
        int s = src[e], d = dst[e];
        int pos = atomicAdd(&cur[d >> 8], 1);
        int2 v; v.x = s; v.y = d;
        ebuf[pos] = v;
    }
}

// ---------------- P4: per-bucket counting sort -> row_ptr, csr_src, dinv -------
__global__ __launch_bounds__(256) void k_p4(const int2* __restrict__ ebuf,
                                            const int* __restrict__ bucketTotal,
                                            int* __restrict__ row_ptr,
                                            int* __restrict__ csr_src,
                                            float* __restrict__ dinv)
{
    __shared__ int2 stash[MAXB];
    __shared__ int sdScan[512];
    __shared__ int bins[256];
    __shared__ int sd[256];
    int b = blockIdx.x, t = threadIdx.x;
    int i2 = t + 256;
    sdScan[t]  = (t  < NBUK) ? bucketTotal[t]  : 0;
    sdScan[i2] = (i2 < NBUK) ? bucketTotal[i2] : 0;
    __syncthreads();
    scan512(sdScan, t);
    int cntb = bucketTotal[b];
    int base = sdScan[b] - cntb;
    bool st = (cntb <= MAXB);
    bins[t] = 0;
    __syncthreads();
    for (int i = t; i < cntb; i += 256){
        int2 ed = ebuf[base + i];
        if (st) stash[i] = ed;
        atomicAdd(&bins[ed.y & 255], 1);
    }
    __syncthreads();
    int a0 = bins[t];
    sd[t] = a0;
    __syncthreads();
    for (int off = 1; off < 256; off <<= 1){
        int v = (t >= off) ? sd[t - off] : 0;
        __syncthreads();
        sd[t] += v;
        __syncthreads();
    }
    int pex = sd[t] - a0;
    int node = b * 256 + t;
    if (node < N_NODES){
        row_ptr[node] = base + pex;
        float d = (float)(a0 + 1);
        dinv[node]  = rsqrtf(d);
    }
    __syncthreads();
    bins[t] = pex;
    __syncthreads();
    for (int i = t; i < cntb; i += 256){
        int2 ed = st ? stash[i] : ebuf[base + i];
        int pos = atomicAdd(&bins[ed.y & 255], 1);
        csr_src[base + pos] = ed.x;
    }
}

// ---------------- MFMA GEMM + fused BN-finalize prologue -----------------------
// tbuf[slice][row][16] = dinv[row] * (BN/ReLU(A[row]) @ W)  -- SLICE-MAJOR out.
// mode 0: A fp32 row-major, no BN (layer 0). mode 1: A fp16 slice-major h;
// block reduces Spart/Qpart -> scale/shift in LDS, BN+ReLU on load.
__global__ __launch_bounds__(256) void k_gemm(const void* __restrict__ Ain,
                                              const unsigned int* __restrict__ wp,
                                              const float* __restrict__ Spart,
                                              const float* __restrict__ Qpart,
                                              const float* __restrict__ gamma,
                                              const float* __restrict__ beta,
                                              const float* __restrict__ dinv,
                                              __half* __restrict__ outh,
                                              int mode)
{
    __shared__ unsigned int lds32[WOFF + 128 * LSTR];   // 52224 B
    __shared__ float sscale[128];
    __shared__ float sshift[128];
    int tid = threadIdx.x;
    int rowBase = blockIdx.x * 64;

    if (mode){
        // fused fin2: reduce slots for this block (stats are L2-resident)
        float* red = (float*)lds32;        // scratch, consumed before staging
        int f = tid & 127;
        const float* sp = (tid < 128) ? Spart : Qpart;
        float acc = 0.f;
        #pragma unroll 16
        for (int s = 0; s < NSLOT; s++)
            acc += sp[s * 128 + f];
        red[tid] = acc;
        __syncthreads();
        if (tid < 128){
            float Sv = red[f];
            float Qv = red[f + 128];
            float mean = Sv * (1.0f / N_NODES);
            float var  = fmaxf(Qv * (1.0f / N_NODES) - mean * mean, 0.0f);
            float inv  = rsqrtf(var + EPSV);
            float gm = gamma[f] * inv;
            sscale[f] = gm;
            sshift[f] = beta[f] - mean * gm;
        }
        __syncthreads();
    }

    if (mode == 0){
        const float* A = (const float*)Ain;
        #pragma unroll
        for (int rep = 0; rep < 8; rep++){
            int f  = rep * 256 + tid;
            int m  = f >> 5;
            int c4 = f & 31;
            int row = rowBase + m;
            if (row >= N_NODES) row = N_NODES - 1;
            float4 v = *(const float4*)(A + (size_t)row * D + c4 * 4);
            __half2 h0 = __floats2half2_rn(v.x, v.y);
            __half2 h1 = __floats2half2_rn(v.z, v.w);
            uint2 u; u.x = *(unsigned int*)&h0; u.y = *(unsigned int*)&h1;
            *(uint2*)&lds32[m * LSTR + 2 * c4] = u;
        }
    } else {
        const __half* A16 = (const __half*)Ain;
        #pragma unroll
        for (int rep = 0; rep < 4; rep++){
            int f  = rep * 256 + tid;
            int m  = f >> 4;
            int c8 = f & 15;              // uint4 slot: features [c8*8, c8*8+8)
            int row = rowBase + m;
            if (row >= N_NODES) row = N_NODES - 1;
            int sc = c8 >> 1, qq = c8 & 1;    // slice, half-of-slice
            uint4 v = *(const uint4*)(A16 + ((size_t)sc * N_NODES + row) * 16 + qq * 8);
            float4 sc0 = *(const float4*)&sscale[c8 * 8];
            float4 sc1 = *(const float4*)&sscale[c8 * 8 + 4];
            float4 sh0 = *(const float4*)&sshift[c8 * 8];
            float4 sh1 = *(const float4*)&sshift[c8 * 8 + 4];
            float2 f0 = __half22float2(*(__half2*)&v.x);
            float2 f1 = __half22float2(*(__half2*)&v.y);
            float2 f2 = __half22float2(*(__half2*)&v.z);
            float2 f3 = __half22float2(*(__half2*)&v.w);
            f0.x = relu_f(fmaf(f0.x, sc0.x, sh0.x));
            f0.y = relu_f(fmaf(f0.y, sc0.y, sh0.y));
            f1.x = relu_f(fmaf(f1.x, sc0.z, sh0.z));
            f1.y = relu_f(fmaf(f1.y, sc0.w, sh0.w));
            f2.x = relu_f(fmaf(f2.x, sc1.x, sh1.x));
            f2.y = relu_f(fmaf(f2.y, sc1.y, sh1.y));
            f3.x = relu_f(fmaf(f3.x, sc1.z, sh1.z));
            f3.y = relu_f(fmaf(f3.y, sc1.w, sh1.w));
            __half2 h0 = __floats2half2_rn(f0.x, f0.y);
            __half2 h1 = __floats2half2_rn(f1.x, f1.y);
            __half2 h2 = __floats2half2_rn(f2.x, f2.y);
            __half2 h3 = __floats2half2_rn(f3.x, f3.y);
            uint4 u;
            u.x = *(unsigned int*)&h0; u.y = *(unsigned int*)&h1;
            u.z = *(unsigned int*)&h2; u.w = *(unsigned int*)&h3;
            *(uint4*)&lds32[m * LSTR + 4 * c8] = u;
        }
    }
    {
        const uint4* gw = (const uint4*)wp;
        #pragma unroll
        for (int rep = 0; rep < 8; rep++){
            int f = rep * 256 + tid;
            int c = f >> 4;
            int q = f & 15;
            uint4 v = gw[f];
            *(uint4*)&lds32[WOFF + c * LSTR + 4 * q] = v;
        }
    }
    __syncthreads();

    int lane = tid & 63, wv = tid >> 6;
    int quad = lane >> 5;
    int ml   = (lane & 31) + (wv & 1) * 32;
    int cA   = (wv >> 1) * 64;
    int c0   = cA + (lane & 31);
    int c1   = c0 + 32;
    const unsigned int* aRow  = lds32 + ml * LSTR;
    const unsigned int* bRow0 = lds32 + WOFF + c0 * LSTR;
    const unsigned int* bRow1 = lds32 + WOFF + c1 * LSTR;
    floatx16 acc0 = {};
    floatx16 acc1 = {};
    #pragma unroll
    for (int ch = 0; ch < 8; ch++){
        int o = ch * 8 + quad * 4;
        half8 af = *(const half8*)(aRow  + o);
        half8 b0 = *(const half8*)(bRow0 + o);
        half8 b1 = *(const half8*)(bRow1 + o);
        acc0 = __builtin_amdgcn_mfma_f32_32x32x16_f16(af, b0, acc0, 0, 0, 0);
        acc1 = __builtin_amdgcn_mfma_f32_32x32x16_f16(af, b1, acc1, 0, 0, 0);
    }
    int sc0i = c0 >> 4, w0 = c0 & 15;
    int sc1i = c1 >> 4, w1 = c1 & 15;
    int rBase = rowBase + (wv & 1) * 32 + 4 * quad;
    #pragma unroll
    for (int r = 0; r < 16; r++){
        int outRow = rBase + (r & 3) + 8 * (r >> 2);
        if (outRow < N_NODES){
            float dv = dinv[outRow];
            outh[((size_t)sc0i * N_NODES + outRow) * 16 + w0] = __float2half(acc0[r] * dv);
            outh[((size_t)sc1i * N_NODES + outRow) * 16 + w1] = __float2half(acc1[r] * dv);
        }
    }
}

__device__ __forceinline__ void accum8(float* acc, uint4 v)
{
    float2 f0 = __half22float2(*(__half2*)&v.x);
    float2 f1 = __half22float2(*(__half2*)&v.y);
    float2 f2 = __half22float2(*(__half2*)&v.z);
    float2 f3 = __half22float2(*(__half2*)&v.w);
    acc[0] += f0.x; acc[1] += f0.y; acc[2] += f1.x; acc[3] += f1.y;
    acc[4] += f2.x; acc[5] += f2.y; acc[6] += f3.x; acc[7] += f3.y;
}

// ---------------- edge aggregation v9: XCD slice-partitioned (T1) --------------
// Table is [8][N][16] slice-major. Block handles ONE 16-feature slice
// (s = blockIdx&7 -> round-robin maps all slice-s blocks to XCD s; the 3.2MB
// slice fits that XCD's 4MB L2 -> gathers become L2 hits). Wave = 32 two-lane
// groups; group walks 4 sequential nodes; per gather instruction the wave moves
// 64x16B = 1KB (same instr/edge as v6). Stats: 5 shfl_xor rounds + 16-wide
// coalesced atomics (50K atomic words total; R4 lesson respected).
__global__ __launch_bounds__(256) void k_agg(const __half* __restrict__ t,
                                             const int* __restrict__ row_ptr,
                                             const int* __restrict__ csr_src,
                                             const float* __restrict__ dinv,
                                             const float* __restrict__ bias,
                                             __half* __restrict__ outb,
                                             float* __restrict__ Spart,
                                             float* __restrict__ Qpart)
{
    __shared__ float ldsS[4][16];
    __shared__ float ldsQ[4][16];
    int tid  = threadIdx.x;
    int lane = tid & 63;
    int wv   = tid >> 6;
    int q    = lane & 1;           // half-of-slice: features [q*8, q*8+8)
    int g    = lane >> 1;          // group 0..31
    int s    = blockIdx.x & 7;     // slice -> XCD affinity
    int chunk = blockIdx.x >> 3;
    const uint4* t4 = (const uint4*)t;
    uint4* out4 = (uint4*)outb;
    size_t sbase = (size_t)s * N_NODES * 2;   // uint4 units: 2 per node-slice

    float4 bia = ((const float4*)bias)[s * 4 + 2 * q];
    float4 bib = ((const float4*)bias)[s * 4 + 2 * q + 1];

    float sa[8] = {0.f,0.f,0.f,0.f,0.f,0.f,0.f,0.f};
    float qa[8] = {0.f,0.f,0.f,0.f,0.f,0.f,0.f,0.f};

    int i0 = chunk * CHUNK + wv * 128 + g * 4;   // 4 sequential nodes per group

    for (int n = 0; n < 4; n++){
        int i = i0 + n;
        if (i < N_NODES){
            int p  = row_ptr[i];
            int pe = row_ptr[i + 1];
            float acc[8];
            {   // self row-slice (pre-scaled by dinv[i] already)
                uint4 v = t4[sbase + (size_t)i * 2 + q];
                float2 f0 = __half22float2(*(__half2*)&v.x);
                float2 f1 = __half22float2(*(__half2*)&v.y);
                float2 f2 = __half22float2(*(__half2*)&v.z);
                float2 f3 = __half22float2(*(__half2*)&v.w);
                acc[0] = f0.x; acc[1] = f0.y; acc[2] = f1.x; acc[3] = f1.y;
                acc[4] = f2.x; acc[5] = f2.y; acc[6] = f3.x; acc[7] = f3.y;
            }
            for (; p + 4 <= pe; p += 4){
                int s0 = csr_src[p],     s1 = csr_src[p + 1];
                int s2 = csr_src[p + 2], s3 = csr_src[p + 3];
                uint4 v0 = t4[sbase + (size_t)s0 * 2 + q];
                uint4 v1 = t4[sbase + (size_t)s1 * 2 + q];
                uint4 v2 = t4[sbase + (size_t)s2 * 2 + q];
                uint4 v3 = t4[sbase + (size_t)s3 * 2 + q];
                accum8(acc, v0); accum8(acc, v1); accum8(acc, v2); accum8(acc, v3);
            }
            for (; p < pe; ++p){
                int sj = csr_src[p];
                accum8(acc, t4[sbase + (size_t)sj * 2 + q]);
            }
            float dvi = dinv[i];
            acc[0] = fmaf(acc[0], dvi, bia.x);
            acc[1] = fmaf(acc[1], dvi, bia.y);
            acc[2] = fmaf(acc[2], dvi, bia.z);
            acc[3] = fmaf(acc[3], dvi, bia.w);
            acc[4] = fmaf(acc[4], dvi, bib.x);
            acc[5] = fmaf(acc[5], dvi, bib.y);
            acc[6] = fmaf(acc[6], dvi, bib.z);
            acc[7] = fmaf(acc[7], dvi, bib.w);
            __half2 o0 = __floats2half2_rn(acc[0], acc[1]);
            __half2 o1 = __floats2half2_rn(acc[2], acc[3]);
            __half2 o2 = __floats2half2_rn(acc[4], acc[5]);
            __half2 o3 = __floats2half2_rn(acc[6], acc[7]);
            uint4 ov;
            ov.x = *(unsigned int*)&o0; ov.y = *(unsigned int*)&o1;
            ov.z = *(unsigned int*)&o2; ov.w = *(unsigned int*)&o3;
            out4[sbase + (size_t)i * 2 + q] = ov;
            #pragma unroll
            for (int k = 0; k < 8; k++){
                sa[k] += acc[k];
                qa[k]  = fmaf(acc[k], acc[k], qa[k]);
            }
        }
    }

    // reduce over the 32 groups (masks preserve q parity)
    #pragma unroll
    for (int k = 0; k < 8; k++){
        sa[k] += __shfl_xor(sa[k], 2);
        sa[k] += __shfl_xor(sa[k], 4);
        sa[k] += __shfl_xor(sa[k], 8);
        sa[k] += __shfl_xor(sa[k], 16);
        sa[k] += __shfl_xor(sa[k], 32);
        qa[k] += __shfl_xor(qa[k], 2);
        qa[k] += __shfl_xor(qa[k], 4);
        qa[k] += __shfl_xor(qa[k], 8);
        qa[k] += __shfl_xor(qa[k], 16);
        qa[k] += __shfl_xor(qa[k], 32);
    }
    if (g == 0){
        #pragma unroll
        for (int k = 0; k < 8; k++){
            ldsS[wv][q * 8 + k] = sa[k];
            ldsQ[wv][q * 8 + k] = qa[k];
        }
    }
    __syncthreads();
    int slot = chunk & (NSLOT - 1);
    if (tid < 16){
        float v = ldsS[0][tid] + ldsS[1][tid] + ldsS[2][tid] + ldsS[3][tid];
        atomicAdd(&Spart[slot * 128 + s * 16 + tid], v);
    } else if (tid < 32){
        int f = tid - 16;
        float v = ldsQ[0][f] + ldsQ[1][f] + ldsQ[2][f] + ldsQ[3][f];
        atomicAdd(&Qpart[slot * 128 + s * 16 + f], v);
    }
}

// ---------------- TAIL: fused fin2 + per-graph BN+ReLU+mean + MLP head --------
// h is slice-major [8][N][16].
__global__ __launch_bounds__(256) void k_tail(const __half* __restrict__ h,
                                              const int* __restrict__ gstart,
                                              const float* __restrict__ Spart,
                                              const float* __restrict__ Qpart,
                                              const float* __restrict__ gamma,
                                              const float* __restrict__ beta,
                                              const float* __restrict__ W1,
                                              const float* __restrict__ b1,
                                              const float* __restrict__ W2,
                                              const float* __restrict__ b2,
                                              float* __restrict__ out)
{
    __shared__ float part[256];
    __shared__ float z[128];
    __shared__ float red[128];
    __shared__ float sscale[128];
    __shared__ float sshift[128];
    int g = blockIdx.x;
    int tid = threadIdx.x;
    int f = tid & 127;
    int hf = tid >> 7;                // 0/1: row-parity split

    {   // fused fin2
        const float* sp = (tid < 128) ? Spart : Qpart;
        float acc = 0.f;
        #pragma unroll 16
        for (int s = 0; s < NSLOT; s++)
            acc += sp[s * 128 + f];
        part[tid] = acc;
        __syncthreads();
        if (tid < 128){
            float Sv = part[f];
            float Qv = part[f + 128];
            float mean = Sv * (1.0f / N_NODES);
            float var  = fmaxf(Qv * (1.0f / N_NODES) - mean * mean, 0.0f);
            float inv  = rsqrtf(var + EPSV);
            float gm = gamma[f] * inv;
            sscale[f] = gm;
            sshift[f] = beta[f] - mean * gm;
        }
        __syncthreads();
    }

    int s0 = gstart[g], s1 = gstart[g + 1];
    float scv = sscale[f], shv = sshift[f];
    const __half* hp = h + (size_t)(f >> 4) * N_NODES * 16 + (f & 15);
    float acc = 0.f;
    for (int i = s0 + hf; i < s1; i += 2)
        acc += relu_f(fmaf(__half2float(hp[(size_t)i * 16]), scv, shv));
    part[tid] = acc;
    __syncthreads();
    if (tid < 128){
        float c = fmaxf((float)(s1 - s0), 1.0f);
        z[f] = (part[f] + part[f + 128]) / c;
    }
    __syncthreads();
    // head GEMV: thread (f,hf) covers k in [hf*64, hf*64+64)
    float a = 0.f;
    int k0 = hf * 64;
    #pragma unroll 8
    for (int k = k0; k < k0 + 64; k++)
        a = fmaf(z[k], W1[k * D + f], a);
    part[tid] = a;
    __syncthreads();
    if (tid < 128){
        float av = relu_f(part[f] + part[f + 128] + b1[f]);
        red[f] = av * W2[f];
    }
    __syncthreads();
    for (int s2 = 64; s2 > 0; s2 >>= 1){
        if (tid < s2) red[tid] += red[tid + s2];
        __syncthreads();
    }
    if (tid == 0) out[g] = red[0] + b2[0];
}

extern "C" void kernel_launch(void* const* d_in, const int* in_sizes, int n_in,
                              void* d_out, int out_size, void* d_ws, size_t ws_size,
                              hipStream_t stream)
{
    const float* x      = (const float*)d_in[0];
    const int*   ei     = (const int*)d_in[1];
    const int*   batch  = (const int*)d_in[2];
    const float* Ws     = (const float*)d_in[3];
    const float* bs     = (const float*)d_in[4];
    const float* gammas = (const float*)d_in[5];
    const float* betas  = (const float*)d_in[6];
    const float* W1     = (const float*)d_in[7];
    const float* b1     = (const float*)d_in[8];
    const float* W2     = (const float*)d_in[9];
    const float* b2     = (const float*)d_in[10];
    float* out = (float*)d_out;

    const int* src = ei;
    const int* dst = ei + N_EDGES;

    char* w = (char*)d_ws;
    size_t off = 0;
    auto alloc = [&](size_t bytes) -> void* {
        void* p = w + off;
        off += (bytes + 255) & ~(size_t)255;
        return p;
    };
    int*   row_ptr     = (int*)  alloc((size_t)(N_NODES + 1) * 4);
    float* dinv        = (float*)alloc((size_t)N_NODES * 4);
    int*   csr_src     = (int*)  alloc((size_t)N_EDGES * 4);
    int*   blockHist   = (int*)  alloc((size_t)NBLK * NBUK * 4);
    int*   colScan     = (int*)  alloc((size_t)NBLK * NBUK * 4);
    int*   bucketTotal = (int*)  alloc((size_t)NBUK * 4);
    unsigned int* wpack = (unsigned int*)alloc((size_t)3 * 128 * 64 * 4);
    int*   gstart      = (int*)  alloc((size_t)(N_GRAPHS + 1) * 4);
    size_t zoff = off;                       // --- zero-span start ---
    float* stats       = (float*)alloc((size_t)3 * 2 * NSLOT * 128 * 4); // per layer: Spart, Qpart
    size_t zend = off;                       // --- zero-span end ---
    __half* tbuf       = (__half*)alloc((size_t)N_NODES * 128 * 2);  // fp16 gather table, slice-major
    __half* hbuf       = (__half*)alloc((size_t)N_NODES * 128 * 2);  // fp16 h, slice-major
    if (off > ws_size) return;

    // alias scratch (consumed before tbuf is first written; stream-ordered)
    int2* ebuf = (int2*)tbuf;    // 6.4 MB < 25.6 MB

    k_front<<<NBLK + 96, 256, 0, stream>>>(dst, blockHist, Ws, wpack,
                                           (unsigned int*)(w + zoff),
                                           (int)((zend - zoff) >> 2),
                                           batch, gstart, row_ptr);
    k_p2a<<<NBUK, 256, 0, stream>>>(blockHist, colScan, bucketTotal);
    k_p3 <<<NBLK, 256, 0, stream>>>(src, dst, colScan, bucketTotal, ebuf);
    k_p4 <<<NBUK, 256, 0, stream>>>(ebuf, bucketTotal, row_ptr, csr_src, dinv);

    const void* curIn = (const void*)x;
    for (int l = 0; l < 3; l++){
        float* Sp = stats + (size_t)l * 2 * NSLOT * 128;
        float* Qp = Sp + NSLOT * 128;
        float* Spm = stats + (size_t)(l - 1) * 2 * NSLOT * 128;   // prev layer (l>=1)
        float* Qpm = Spm + NSLOT * 128;
        k_gemm<<<(N_NODES + 63) / 64, 256, 0, stream>>>(
            curIn, wpack + l * 8192,
            l ? Spm : nullptr,
            l ? Qpm : nullptr,
            l ? gammas + (l - 1) * 128 : nullptr,
            l ? betas  + (l - 1) * 128 : nullptr,
            dinv, tbuf, l ? 1 : 0);
        k_agg<<<NSLICE * NCHUNK, 256, 0, stream>>>(
            tbuf, row_ptr, csr_src, dinv,
            bs + l * 128, hbuf, Sp, Qp);
        curIn = (const void*)hbuf;
    }

    {
        float* Sp2 = stats + (size_t)2 * 2 * NSLOT * 128;
        float* Qp2 = Sp2 + NSLOT * 128;
        k_tail<<<N_GRAPHS, 256, 0, stream>>>(hbuf, gstart,
                                             Sp2, Qp2,
                                             gammas + 2 * 128, betas + 2 * 128,
                                             W1, b1, W2, b2, out);
    }
}

// Round 8
// 406.755 us; speedup vs baseline: 1.2276x; 1.2276x over previous
//
#include <hip/hip_runtime.h>
#include <hip/hip_bf16.h>
#include <hip/hip_fp16.h>

#define N_NODES 100000
#define N_EDGES 800000
#define N_GRAPHS 512
#define D 128
#define EPSV 1e-5f

#define NBLK 256          // edge-chunk blocks
#define EPB  3125         // edges per block
#define NSB  391          // scan blocks: ceil(100000/256)

// MFMA GEMM LDS layout (dwords): Ah 64 rows x 68dw, Wt2 128 cols x 68dw
#define LSTR 68
#define WOFF 4352

#define NSLOT 64          // stats scatter slots (3125 blocks / 64 ~ 49 per slot)

typedef _Float16 half8 __attribute__((ext_vector_type(8)));
typedef float floatx16 __attribute__((ext_vector_type(16)));

__device__ __forceinline__ float relu_f(float x){ return fmaxf(x, 0.0f); }

// ---------------- FRONT v2: deg histogram (blocks 0..255) | wprep+zero+gstart --
// deg[] pre-zeroed via hipMemsetAsync. 800K device-scope atomicAdds into 400KB
// (avg 8 adds/address, L2-resident) -- NOT the R4 small-region pathology.
__global__ __launch_bounds__(256) void k_front(const int* __restrict__ dst,
                                               int* __restrict__ deg,
                                               const float* __restrict__ Ws,
                                               unsigned int* __restrict__ wpack,
                                               unsigned int* __restrict__ zbase,
                                               int zn,
                                               const int* __restrict__ batch,
                                               int* __restrict__ gstart,
                                               int* __restrict__ row_ptr)
{
    int j = blockIdx.x, t = threadIdx.x;
    if (j < NBLK){
        int e0 = j * EPB;
        for (int e = e0 + t; e < e0 + EPB; e += 256)
            atomicAdd(&deg[dst[e]], 1);
    } else {
        int b = j - NBLK;                 // 0..95
        int idx = b * 256 + t;
        if (idx == 0){
            row_ptr[N_NODES] = N_EDGES;
            gstart[N_GRAPHS] = N_NODES;
        }
        if (idx < 3 * 128 * 64){
            int l  = idx >> 13;
            int r  = idx & 8191;
            int c  = r >> 6;
            int k2 = r & 63;
            const float* W = Ws + l * D * D;
            __half2 hh = __floats2half2_rn(W[(size_t)(2 * k2) * D + c],
                                           W[(size_t)(2 * k2 + 1) * D + c]);
            wpack[idx] = *(unsigned int*)&hh;
        }
        int stride = 96 * 256;
        for (int i = idx; i < zn; i += stride) zbase[i] = 0u;
        if (idx < N_GRAPHS){
            int g = idx;
            int lo = 0, hi = N_NODES;
            while (lo < hi){ int m = (lo + hi) >> 1; if (batch[m] < g) lo = m + 1; else hi = m; }
            gstart[g] = lo;
        }
    }
}

// ---------------- SCAN A: block-local exclusive scan of deg -> cursor(pex), partials
__global__ __launch_bounds__(256) void k_scanA(const int* __restrict__ deg,
                                               int* __restrict__ cursor,
                                               int* __restrict__ partials)
{
    __shared__ int sd[256];
    int b = blockIdx.x, t = threadIdx.x;
    int node = b * 256 + t;
    int v = (node < N_NODES) ? deg[node] : 0;
    sd[t] = v;
    __syncthreads();
    for (int off = 1; off < 256; off <<= 1){
        int u = (t >= off) ? sd[t - off] : 0;
        __syncthreads();
        sd[t] += u;
        __syncthreads();
    }
    if (node < N_NODES) cursor[node] = sd[t] - v;   // local exclusive prefix
    if (t == 255) partials[b] = sd[255];
}

// ---------------- SCAN B: scan partials; write row_ptr, cursor, dinv -----------
__global__ __launch_bounds__(256) void k_scanB(const int* __restrict__ deg,
                                               const int* __restrict__ partials,
                                               int* __restrict__ cursor,
                                               int* __restrict__ row_ptr,
                                               float* __restrict__ dinv)
{
    __shared__ int sd[512];
    int b = blockIdx.x, t = threadIdx.x;
    int i2 = t + 256;
    sd[t]  = (t  < NSB) ? partials[t]  : 0;
    sd[i2] = (i2 < NSB) ? partials[i2] : 0;
    __syncthreads();
    for (int off = 1; off < 512; off <<= 1){
        int v1 = (t  >= off) ? sd[t  - off] : 0;
        int v2 = (i2 >= off) ? sd[i2 - off] : 0;
        __syncthreads();
        sd[t]  += v1;
        sd[i2] += v2;
        __syncthreads();
    }
    int base = sd[b] - partials[b];     // exclusive prefix of this block
    int node = b * 256 + t;
    if (node < N_NODES){
        int rp = base + cursor[node];
        row_ptr[node] = rp;
        cursor[node]  = rp;
        dinv[node]    = rsqrtf((float)(deg[node] + 1));
    }
}

// ---------------- SCATTER: edges -> csr_src via atomic cursors -----------------
__global__ __launch_bounds__(256) void k_scatter(const int* __restrict__ src,
                                                 const int* __restrict__ dst,
                                                 int* __restrict__ cursor,
                                                 int* __restrict__ csr_src)
{
    int j = blockIdx.x, t = threadIdx.x;
    int e0 = j * EPB;
    for (int e = e0 + t; e < e0 + EPB; e += 256){
        int s = src[e], d = dst[e];
        int pos = atomicAdd(&cursor[d], 1);
        csr_src[pos] = s;
    }
}

// ---------------- MFMA GEMM + fused BN-finalize prologue -----------------------
// tbuf[row] = dinv[row] * (BN/ReLU(A[row]) @ W).
// mode 0: A fp32, no BN (layer 0). mode 1: A fp16; block reduces Spart/Qpart
// (NSLOT slots, L2-resident) -> scale/shift in LDS, then BN+ReLU on load.
__global__ __launch_bounds__(256) void k_gemm(const void* __restrict__ Ain,
                                              const unsigned int* __restrict__ wp,
                                              const float* __restrict__ Spart,
                                              const float* __restrict__ Qpart,
                                              const float* __restrict__ gamma,
                                              const float* __restrict__ beta,
                                              const float* __restrict__ dinv,
                                              __half* __restrict__ outh,
                                              int mode)
{
    __shared__ unsigned int lds32[WOFF + 128 * LSTR];   // 52224 B
    __shared__ float sscale[128];
    __shared__ float sshift[128];
    int tid = threadIdx.x;
    int rowBase = blockIdx.x * 64;

    if (mode){
        // fused fin2: reduce slots for this block (stats are L2-resident)
        float* red = (float*)lds32;        // scratch, consumed before staging
        int f = tid & 127;
        const float* sp = (tid < 128) ? Spart : Qpart;
        float acc = 0.f;
        #pragma unroll 16
        for (int s = 0; s < NSLOT; s++)
            acc += sp[s * 128 + f];
        red[tid] = acc;
        __syncthreads();
        if (tid < 128){
            float Sv = red[f];
            float Qv = red[f + 128];
            float mean = Sv * (1.0f / N_NODES);
            float var  = fmaxf(Qv * (1.0f / N_NODES) - mean * mean, 0.0f);
            float inv  = rsqrtf(var + EPSV);
            float gm = gamma[f] * inv;
            sscale[f] = gm;
            sshift[f] = beta[f] - mean * gm;
        }
        __syncthreads();
    }

    if (mode == 0){
        const float* A = (const float*)Ain;
        #pragma unroll
        for (int rep = 0; rep < 8; rep++){
            int f  = rep * 256 + tid;
            int m  = f >> 5;
            int c4 = f & 31;
            int row = rowBase + m;
            if (row >= N_NODES) row = N_NODES - 1;
            float4 v = *(const float4*)(A + (size_t)row * D + c4 * 4);
            __half2 h0 = __floats2half2_rn(v.x, v.y);
            __half2 h1 = __floats2half2_rn(v.z, v.w);
            uint2 u; u.x = *(unsigned int*)&h0; u.y = *(unsigned int*)&h1;
            *(uint2*)&lds32[m * LSTR + 2 * c4] = u;
        }
    } else {
        const __half* A16 = (const __half*)Ain;
        #pragma unroll
        for (int rep = 0; rep < 4; rep++){
            int f  = rep * 256 + tid;
            int m  = f >> 4;
            int c8 = f & 15;
            int row = rowBase + m;
            if (row >= N_NODES) row = N_NODES - 1;
            uint4 v = *(const uint4*)(A16 + (size_t)row * D + c8 * 8);
            float4 sc0 = *(const float4*)&sscale[c8 * 8];
            float4 sc1 = *(const float4*)&sscale[c8 * 8 + 4];
            float4 sh0 = *(const float4*)&sshift[c8 * 8];
            float4 sh1 = *(const float4*)&sshift[c8 * 8 + 4];
            float2 f0 = __half22float2(*(__half2*)&v.x);
            float2 f1 = __half22float2(*(__half2*)&v.y);
            float2 f2 = __half22float2(*(__half2*)&v.z);
            float2 f3 = __half22float2(*(__half2*)&v.w);
            f0.x = relu_f(fmaf(f0.x, sc0.x, sh0.x));
            f0.y = relu_f(fmaf(f0.y, sc0.y, sh0.y));
            f1.x = relu_f(fmaf(f1.x, sc0.z, sh0.z));
            f1.y = relu_f(fmaf(f1.y, sc0.w, sh0.w));
            f2.x = relu_f(fmaf(f2.x, sc1.x, sh1.x));
            f2.y = relu_f(fmaf(f2.y, sc1.y, sh1.y));
            f3.x = relu_f(fmaf(f3.x, sc1.z, sh1.z));
            f3.y = relu_f(fmaf(f3.y, sc1.w, sh1.w));
            __half2 h0 = __floats2half2_rn(f0.x, f0.y);
            __half2 h1 = __floats2half2_rn(f1.x, f1.y);
            __half2 h2 = __floats2half2_rn(f2.x, f2.y);
            __half2 h3 = __floats2half2_rn(f3.x, f3.y);
            uint4 u;
            u.x = *(unsigned int*)&h0; u.y = *(unsigned int*)&h1;
            u.z = *(unsigned int*)&h2; u.w = *(unsigned int*)&h3;
            *(uint4*)&lds32[m * LSTR + 4 * c8] = u;
        }
    }
    {
        const uint4* gw = (const uint4*)wp;
        #pragma unroll
        for (int rep = 0; rep < 8; rep++){
            int f = rep * 256 + tid;
            int c = f >> 4;
            int q = f & 15;
            uint4 v = gw[f];
            *(uint4*)&lds32[WOFF + c * LSTR + 4 * q] = v;
        }
    }
    __syncthreads();

    int lane = tid & 63, wv = tid >> 6;
    int quad = lane >> 5;
    int ml   = (lane & 31) + (wv & 1) * 32;
    int cA   = (wv >> 1) * 64;
    int c0   = cA + (lane & 31);
    int c1   = c0 + 32;
    const unsigned int* aRow  = lds32 + ml * LSTR;
    const unsigned int* bRow0 = lds32 + WOFF + c0 * LSTR;
    const unsigned int* bRow1 = lds32 + WOFF + c1 * LSTR;
    floatx16 acc0 = {};
    floatx16 acc1 = {};
    #pragma unroll
    for (int ch = 0; ch < 8; ch++){
        int o = ch * 8 + quad * 4;
        half8 af = *(const half8*)(aRow  + o);
        half8 b0 = *(const half8*)(bRow0 + o);
        half8 b1 = *(const half8*)(bRow1 + o);
        acc0 = __builtin_amdgcn_mfma_f32_32x32x16_f16(af, b0, acc0, 0, 0, 0);
        acc1 = __builtin_amdgcn_mfma_f32_32x32x16_f16(af, b1, acc1, 0, 0, 0);
    }
    int rBase = rowBase + (wv & 1) * 32 + 4 * quad;
    #pragma unroll
    for (int r = 0; r < 16; r++){
        int outRow = rBase + (r & 3) + 8 * (r >> 2);
        if (outRow < N_NODES){
            float dv = dinv[outRow];
            outh[(size_t)outRow * D + c0] = __float2half(acc0[r] * dv);
            outh[(size_t)outRow * D + c1] = __float2half(acc1[r] * dv);
        }
    }
}

__device__ __forceinline__ void accum8(float* acc, uint4 v)
{
    float2 f0 = __half22float2(*(__half2*)&v.x);
    float2 f1 = __half22float2(*(__half2*)&v.y);
    float2 f2 = __half22float2(*(__half2*)&v.z);
    float2 f3 = __half22float2(*(__half2*)&v.w);
    acc[0] += f0.x; acc[1] += f0.y; acc[2] += f1.x; acc[3] += f1.y;
    acc[4] += f2.x; acc[5] += f2.y; acc[6] += f3.x; acc[7] += f3.y;
}

// ---------------- edge aggregation v6 (proven; R5-exact) -----------------------
// 16-lane groups, 16B/lane full-row gathers (256B rows, 100% line utilization),
// sequential 2 nodes/group, LDS stats epilogue, ONE coalesced 128-wide atomic
// set per block. Structural alternatives all measured worse:
//   per-wave scalar atomics (R4: 147us), dual-node interleave (R6: 50us, VGPR
//   36->56 occupancy loss), slice-partition w/ XCD affinity (R7: 92us, 4x line
//   waste + no affinity control). DO NOT touch.
__global__ __launch_bounds__(256) void k_agg(const __half* __restrict__ t,
                                             const int* __restrict__ row_ptr,
                                             const int* __restrict__ csr_src,
                                             const float* __restrict__ dinv,
                                             const float* __restrict__ bias,
                                             __half* __restrict__ outb,
                                             float* __restrict__ Spart,
                                             float* __restrict__ Qpart)
{
    __shared__ float ldsS[4][128];
    __shared__ float ldsQ[4][128];
    int tid  = threadIdx.x;
    int lane = tid & 63;
    int wv   = tid >> 6;
    int q    = lane & 15;          // feature slot
    int g    = lane >> 4;          // group 0..3
    const uint4* t4 = (const uint4*)t;
    uint4* out4 = (uint4*)outb;

    float4 bia = ((const float4*)bias)[2 * q];
    float4 bib = ((const float4*)bias)[2 * q + 1];

    float sa[8] = {0.f,0.f,0.f,0.f,0.f,0.f,0.f,0.f};
    float qa[8] = {0.f,0.f,0.f,0.f,0.f,0.f,0.f,0.f};

    int i0 = blockIdx.x * 32 + wv * 8 + g * 2;   // group covers 2 nodes

    for (int n = 0; n < 2; n++){
        int i  = i0 + n;
        int p  = row_ptr[i];
        int pe = row_ptr[i + 1];
        float acc[8];
        {   // self row (pre-scaled by dinv[i] already)
            uint4 v = t4[(size_t)i * 16 + q];
            float2 f0 = __half22float2(*(__half2*)&v.x);
            float2 f1 = __half22float2(*(__half2*)&v.y);
            float2 f2 = __half22float2(*(__half2*)&v.z);
            float2 f3 = __half22float2(*(__half2*)&v.w);
            acc[0] = f0.x; acc[1] = f0.y; acc[2] = f1.x; acc[3] = f1.y;
            acc[4] = f2.x; acc[5] = f2.y; acc[6] = f3.x; acc[7] = f3.y;
        }
        for (; p + 4 <= pe; p += 4){
            int s0 = csr_src[p],     s1 = csr_src[p + 1];
            int s2 = csr_src[p + 2], s3 = csr_src[p + 3];
            uint4 v0 = t4[(size_t)s0 * 16 + q];
            uint4 v1 = t4[(size_t)s1 * 16 + q];
            uint4 v2 = t4[(size_t)s2 * 16 + q];
            uint4 v3 = t4[(size_t)s3 * 16 + q];
            accum8(acc, v0); accum8(acc, v1); accum8(acc, v2); accum8(acc, v3);
        }
        for (; p < pe; ++p){
            int s = csr_src[p];
            uint4 v = t4[(size_t)s * 16 + q];
            accum8(acc, v);
        }
        float dvi = dinv[i];
        acc[0] = fmaf(acc[0], dvi, bia.x);
        acc[1] = fmaf(acc[1], dvi, bia.y);
        acc[2] = fmaf(acc[2], dvi, bia.z);
        acc[3] = fmaf(acc[3], dvi, bia.w);
        acc[4] = fmaf(acc[4], dvi, bib.x);
        acc[5] = fmaf(acc[5], dvi, bib.y);
        acc[6] = fmaf(acc[6], dvi, bib.z);
        acc[7] = fmaf(acc[7], dvi, bib.w);
        __half2 o0 = __floats2half2_rn(acc[0], acc[1]);
        __half2 o1 = __floats2half2_rn(acc[2], acc[3]);
        __half2 o2 = __floats2half2_rn(acc[4], acc[5]);
        __half2 o3 = __floats2half2_rn(acc[6], acc[7]);
        uint4 ov;
        ov.x = *(unsigned int*)&o0; ov.y = *(unsigned int*)&o1;
        ov.z = *(unsigned int*)&o2; ov.w = *(unsigned int*)&o3;
        out4[(size_t)i * 16 + q] = ov;
        #pragma unroll
        for (int k = 0; k < 8; k++){
            sa[k] += acc[k];
            qa[k]  = fmaf(acc[k], acc[k], qa[k]);
        }
    }

    // combine the 4 groups' per-feature stats within the wave
    #pragma unroll
    for (int k = 0; k < 8; k++){
        sa[k] += __shfl_xor(sa[k], 16);
        sa[k] += __shfl_xor(sa[k], 32);
        qa[k] += __shfl_xor(qa[k], 16);
        qa[k] += __shfl_xor(qa[k], 32);
    }
    if (g == 0){
        #pragma unroll
        for (int k = 0; k < 8; k++){
            ldsS[wv][8 * q + k] = sa[k];
            ldsQ[wv][8 * q + k] = qa[k];
        }
    }
    __syncthreads();
    int slotBase = (blockIdx.x & (NSLOT - 1)) * 128;
    if (tid < 128){
        float s = ldsS[0][tid] + ldsS[1][tid] + ldsS[2][tid] + ldsS[3][tid];
        atomicAdd(&Spart[slotBase + tid], s);
    } else {
        int f = tid - 128;
        float qv = ldsQ[0][f] + ldsQ[1][f] + ldsQ[2][f] + ldsQ[3][f];
        atomicAdd(&Qpart[slotBase + f], qv);
    }
}

// ---------------- TAIL: fused fin2 + per-graph BN+ReLU+mean + MLP head --------
__global__ __launch_bounds__(256) void k_tail(const __half* __restrict__ h,
                                              const int* __restrict__ gstart,
                                              const float* __restrict__ Spart,
                                              const float* __restrict__ Qpart,
                                              const float* __restrict__ gamma,
                                              const float* __restrict__ beta,
                                              const float* __restrict__ W1,
                                              const float* __restrict__ b1,
                                              const float* __restrict__ W2,
                                              const float* __restrict__ b2,
                                              float* __restrict__ out)
{
    __shared__ float part[256];
    __shared__ float z[128];
    __shared__ float red[128];
    __shared__ float sscale[128];
    __shared__ float sshift[128];
    int g = blockIdx.x;
    int tid = threadIdx.x;
    int f = tid & 127;
    int hf = tid >> 7;                // 0/1: row-parity split

    {   // fused fin2
        const float* sp = (tid < 128) ? Spart : Qpart;
        float acc = 0.f;
        #pragma unroll 16
        for (int s = 0; s < NSLOT; s++)
            acc += sp[s * 128 + f];
        part[tid] = acc;
        __syncthreads();
        if (tid < 128){
            float Sv = part[f];
            float Qv = part[f + 128];
            float mean = Sv * (1.0f / N_NODES);
            float var  = fmaxf(Qv * (1.0f / N_NODES) - mean * mean, 0.0f);
            float inv  = rsqrtf(var + EPSV);
            float gm = gamma[f] * inv;
            sscale[f] = gm;
            sshift[f] = beta[f] - mean * gm;
        }
        __syncthreads();
    }

    int s0 = gstart[g], s1 = gstart[g + 1];
    float scv = sscale[f], shv = sshift[f];
    float acc = 0.f;
    for (int i = s0 + hf; i < s1; i += 2)
        acc += relu_f(fmaf(__half2float(h[(size_t)i * D + f]), scv, shv));
    part[tid] = acc;
    __syncthreads();
    if (tid < 128){
        float c = fmaxf((float)(s1 - s0), 1.0f);
        z[f] = (part[f] + part[f + 128]) / c;
    }
    __syncthreads();
    // head GEMV: thread (f,hf) covers k in [hf*64, hf*64+64)
    float a = 0.f;
    int k0 = hf * 64;
    #pragma unroll 8
    for (int k = k0; k < k0 + 64; k++)
        a = fmaf(z[k], W1[k * D + f], a);
    part[tid] = a;
    __syncthreads();
    if (tid < 128){
        float av = relu_f(part[f] + part[f + 128] + b1[f]);
        red[f] = av * W2[f];
    }
    __syncthreads();
    for (int s2 = 64; s2 > 0; s2 >>= 1){
        if (tid < s2) red[tid] += red[tid + s2];
        __syncthreads();
    }
    if (tid == 0) out[g] = red[0] + b2[0];
}

extern "C" void kernel_launch(void* const* d_in, const int* in_sizes, int n_in,
                              void* d_out, int out_size, void* d_ws, size_t ws_size,
                              hipStream_t stream)
{
    const float* x      = (const float*)d_in[0];
    const int*   ei     = (const int*)d_in[1];
    const int*   batch  = (const int*)d_in[2];
    const float* Ws     = (const float*)d_in[3];
    const float* bs     = (const float*)d_in[4];
    const float* gammas = (const float*)d_in[5];
    const float* betas  = (const float*)d_in[6];
    const float* W1     = (const float*)d_in[7];
    const float* b1     = (const float*)d_in[8];
    const float* W2     = (const float*)d_in[9];
    const float* b2     = (const float*)d_in[10];
    float* out = (float*)d_out;

    const int* src = ei;
    const int* dst = ei + N_EDGES;

    char* w = (char*)d_ws;
    size_t off = 0;
    auto alloc = [&](size_t bytes) -> void* {
        void* p = w + off;
        off += (bytes + 255) & ~(size_t)255;
        return p;
    };
    int*   row_ptr     = (int*)  alloc((size_t)(N_NODES + 1) * 4);
    float* dinv        = (float*)alloc((size_t)N_NODES * 4);
    int*   csr_src     = (int*)  alloc((size_t)N_EDGES * 4);
    int*   deg         = (int*)  alloc((size_t)N_NODES * 4);     // memset-zeroed
    int*   cursor      = (int*)  alloc((size_t)N_NODES * 4);
    int*   partials    = (int*)  alloc((size_t)512 * 4);
    unsigned int* wpack = (unsigned int*)alloc((size_t)3 * 128 * 64 * 4);
    int*   gstart      = (int*)  alloc((size_t)(N_GRAPHS + 1) * 4);
    size_t zoff = off;                       // --- zero-span start ---
    float* stats       = (float*)alloc((size_t)3 * 2 * NSLOT * 128 * 4); // per layer: Spart, Qpart
    size_t zend = off;                       // --- zero-span end ---
    __half* tbuf       = (__half*)alloc((size_t)N_NODES * 128 * 2);  // fp16 gather table (dinv-scaled)
    __half* hbuf       = (__half*)alloc((size_t)N_NODES * 128 * 2);  // fp16 h (pre-BN)
    if (off > ws_size) return;

    // deg must be zero before k_front's atomic histogram (stream-ordered,
    // graph-capturable memset node; no sync APIs involved)
    hipMemsetAsync(deg, 0, (size_t)N_NODES * 4, stream);

    k_front<<<NBLK + 96, 256, 0, stream>>>(dst, deg, Ws, wpack,
                                           (unsigned int*)(w + zoff),
                                           (int)((zend - zoff) >> 2),
                                           batch, gstart, row_ptr);
    k_scanA<<<NSB, 256, 0, stream>>>(deg, cursor, partials);
    k_scanB<<<NSB, 256, 0, stream>>>(deg, partials, cursor, row_ptr, dinv);
    k_scatter<<<NBLK, 256, 0, stream>>>(src, dst, cursor, csr_src);

    const void* curIn = (const void*)x;
    for (int l = 0; l < 3; l++){
        float* Sp = stats + (size_t)l * 2 * NSLOT * 128;
        float* Qp = Sp + NSLOT * 128;
        float* Spm = stats + (size_t)(l - 1) * 2 * NSLOT * 128;   // prev layer (l>=1)
        float* Qpm = Spm + NSLOT * 128;
        k_gemm<<<(N_NODES + 63) / 64, 256, 0, stream>>>(
            curIn, wpack + l * 8192,
            l ? Spm : nullptr,
            l ? Qpm : nullptr,
            l ? gammas + (l - 1) * 128 : nullptr,
            l ? betas  + (l - 1) * 128 : nullptr,
            dinv, tbuf, l ? 1 : 0);
        k_agg<<<N_NODES / 32, 256, 0, stream>>>(
            tbuf, row_ptr, csr_src, dinv,
            bs + l * 128, hbuf, Sp, Qp);
        curIn = (const void*)hbuf;
    }

    {
        float* Sp2 = stats + (size_t)2 * 2 * NSLOT * 128;
        float* Qp2 = Sp2 + NSLOT * 128;
        k_tail<<<N_GRAPHS, 256, 0, stream>>>(hbuf, gstart,
                                             Sp2, Qp2,
                                             gammas + 2 * 128, betas + 2 * 128,
                                             W1, b1, W2, b2, out);
    }
}

// Round 9
// 345.484 us; speedup vs baseline: 1.4453x; 1.1773x over previous
//
#include <hip/hip_runtime.h>
#include <hip/hip_bf16.h>
#include <hip/hip_fp16.h>

#define N_NODES 100000
#define N_EDGES 800000
#define N_GRAPHS 512
#define D 128
#define EPSV 1e-5f

// radix-bucket CSR build params (256-node buckets)
#define NBLK 256
#define EPB  3125
#define NBUK 391          // ceil(100000/256)
#define MAXB 3072

// MFMA GEMM LDS layout (dwords): Ah 64 rows x 68dw, Wt2 128 cols x 68dw
#define LSTR 68
#define WOFF 4352

#define NSLOT 64          // stats scatter slots (3125 blocks / 64 ~ 49 per slot)

typedef _Float16 half8 __attribute__((ext_vector_type(8)));
typedef float floatx16 __attribute__((ext_vector_type(16)));

__device__ __forceinline__ float relu_f(float x){ return fmaxf(x, 0.0f); }

// inclusive scan of sd[0..511] with 256 threads
__device__ __forceinline__ void scan512(int* sd, int t)
{
    for (int off = 1; off < 512; off <<= 1){
        int i2 = t + 256;
        int v1 = (t  >= off) ? sd[t  - off] : 0;
        int v2 = (i2 >= off) ? sd[i2 - off] : 0;
        __syncthreads();
        sd[t]  += v1;
        sd[i2] += v2;
        __syncthreads();
    }
}

// ---------------- FRONT: p1 histogram (blocks 0..255) | wprep+zero+gstart ------
__global__ __launch_bounds__(256) void k_front(const int* __restrict__ dst,
                                               int* __restrict__ blockHist,
                                               const float* __restrict__ Ws,
                                               unsigned int* __restrict__ wpack,
                                               unsigned int* __restrict__ zbase,
                                               int zn,
                                               const int* __restrict__ batch,
                                               int* __restrict__ gstart,
                                               int* __restrict__ row_ptr)
{
    __shared__ int h[NBUK];
    int j = blockIdx.x, t = threadIdx.x;
    if (j < NBLK){
        for (int u = t; u < NBUK; u += 256) h[u] = 0;
        __syncthreads();
        int e0 = j * EPB;
        for (int e = e0 + t; e < e0 + EPB; e += 256)
            atomicAdd(&h[dst[e] >> 8], 1);
        __syncthreads();
        for (int u = t; u < NBUK; u += 256) blockHist[j * NBUK + u] = h[u];
    } else {
        int b = j - NBLK;                 // 0..95
        int idx = b * 256 + t;
        if (idx == 0){
            row_ptr[N_NODES] = N_EDGES;
            gstart[N_GRAPHS] = N_NODES;
        }
        if (idx < 3 * 128 * 64){
            int l  = idx >> 13;
            int r  = idx & 8191;
            int c  = r >> 6;
            int k2 = r & 63;
            const float* W = Ws + l * D * D;
            __half2 hh = __floats2half2_rn(W[(size_t)(2 * k2) * D + c],
                                           W[(size_t)(2 * k2 + 1) * D + c]);
            wpack[idx] = *(unsigned int*)&hh;
        }
        int stride = 96 * 256;
        for (int i = idx; i < zn; i += stride) zbase[i] = 0u;
        if (idx < N_GRAPHS){
            int g = idx;
            int lo = 0, hi = N_NODES;
            while (lo < hi){ int m = (lo + hi) >> 1; if (batch[m] < g) lo = m + 1; else hi = m; }
            gstart[g] = lo;
        }
    }
}

// ---------------- P2a: per-bucket column scan (NBUK blocks, parallel) ----------
__global__ __launch_bounds__(256) void k_p2a(const int* __restrict__ blockHist,
                                             int* __restrict__ colScan,
                                             int* __restrict__ bucketTotal)
{
    __shared__ int sd[256];
    int b = blockIdx.x, t = threadIdx.x;
    int v = blockHist[t * NBUK + b];
    sd[t] = v;
    __syncthreads();
    for (int off = 1; off < 256; off <<= 1){
        int u = (t >= off) ? sd[t - off] : 0;
        __syncthreads();
        sd[t] += u;
        __syncthreads();
    }
    colScan[t * NBUK + b] = sd[t] - v;
    if (t == 255) bucketTotal[b] = sd[255];
}

// ---------------- P3: scatter edges into bucket-sorted ebuf (LDS cursors) ------
__global__ __launch_bounds__(256) void k_p3(const int* __restrict__ src,
                                            const int* __restrict__ dst,
                                            const int* __restrict__ colScan,
                                            const int* __restrict__ bucketTotal,
                                            int2* __restrict__ ebuf)
{
    __shared__ int sd[512];
    __shared__ int cur[NBUK];
    int j = blockIdx.x, t = threadIdx.x;
    int i2 = t + 256;
    sd[t]  = (t  < NBUK) ? bucketTotal[t]  : 0;
    sd[i2] = (i2 < NBUK) ? bucketTotal[i2] : 0;
    __syncthreads();
    scan512(sd, t);
    if (t < NBUK)
        cur[t]  = (sd[t]  - bucketTotal[t])  + colScan[j * NBUK + t];
    if (i2 < NBUK)
        cur[i2] = (sd[i2] - bucketTotal[i2]) + colScan[j * NBUK + i2];
    __syncthreads();
    int e0 = j * EPB;
    for (int e = e0 + t; e < e0 + EPB; e += 256){
        int s = src[e], d = dst[e];
        int pos = atomicAdd(&cur[d >> 8], 1);
        int2 v; v.x = s; v.y = d;
        ebuf[pos] = v;
    }
}

// ---------------- P4: per-bucket counting sort -> row_ptr, csr_src, dinv -------
__global__ __launch_bounds__(256) void k_p4(const int2* __restrict__ ebuf,
                                            const int* __restrict__ bucketTotal,
                                            int* __restrict__ row_ptr,
                                            int* __restrict__ csr_src,
                                            float* __restrict__ dinv)
{
    __shared__ int2 stash[MAXB];
    __shared__ int sdScan[512];
    __shared__ int bins[256];
    __shared__ int sd[256];
    int b = blockIdx.x, t = threadIdx.x;
    int i2 = t + 256;
    sdScan[t]  = (t  < NBUK) ? bucketTotal[t]  : 0;
    sdScan[i2] = (i2 < NBUK) ? bucketTotal[i2] : 0;
    __syncthreads();
    scan512(sdScan, t);
    int cntb = bucketTotal[b];
    int base = sdScan[b] - cntb;
    bool st = (cntb <= MAXB);
    bins[t] = 0;
    __syncthreads();
    for (int i = t; i < cntb; i += 256){
        int2 ed = ebuf[base + i];
        if (st) stash[i] = ed;
        atomicAdd(&bins[ed.y & 255], 1);
    }
    __syncthreads();
    int a0 = bins[t];
    sd[t] = a0;
    __syncthreads();
    for (int off = 1; off < 256; off <<= 1){
        int v = (t >= off) ? sd[t - off] : 0;
        __syncthreads();
        sd[t] += v;
        __syncthreads();
    }
    int pex = sd[t] - a0;
    int node = b * 256 + t;
    if (node < N_NODES){
        row_ptr[node] = base + pex;
        float d = (float)(a0 + 1);
        dinv[node]  = rsqrtf(d);
    }
    __syncthreads();
    bins[t] = pex;
    __syncthreads();
    for (int i = t; i < cntb; i += 256){
        int2 ed = st ? stash[i] : ebuf[base + i];
        int pos = atomicAdd(&bins[ed.y & 255], 1);
        csr_src[base + pos] = ed.x;
    }
}

// ---------------- MFMA GEMM + fused BN-finalize prologue -----------------------
// tbuf[row] = dinv[row] * (BN/ReLU(A[row]) @ W).
// mode 0: A fp32, no BN (layer 0). mode 1: A fp16; block reduces Spart/Qpart
// (NSLOT slots, L2-resident) -> scale/shift in LDS, then BN+ReLU on load.
__global__ __launch_bounds__(256) void k_gemm(const void* __restrict__ Ain,
                                              const unsigned int* __restrict__ wp,
                                              const float* __restrict__ Spart,
                                              const float* __restrict__ Qpart,
                                              const float* __restrict__ gamma,
                                              const float* __restrict__ beta,
                                              const float* __restrict__ dinv,
                                              __half* __restrict__ outh,
                                              int mode)
{
    __shared__ unsigned int lds32[WOFF + 128 * LSTR];   // 52224 B
    __shared__ float sscale[128];
    __shared__ float sshift[128];
    int tid = threadIdx.x;
    int rowBase = blockIdx.x * 64;

    if (mode){
        // fused fin2: reduce slots for this block (stats are L2-resident)
        float* red = (float*)lds32;        // scratch, consumed before staging
        int f = tid & 127;
        const float* sp = (tid < 128) ? Spart : Qpart;
        float acc = 0.f;
        #pragma unroll 16
        for (int s = 0; s < NSLOT; s++)
            acc += sp[s * 128 + f];
        red[tid] = acc;
        __syncthreads();
        if (tid < 128){
            float Sv = red[f];
            float Qv = red[f + 128];
            float mean = Sv * (1.0f / N_NODES);
            float var  = fmaxf(Qv * (1.0f / N_NODES) - mean * mean, 0.0f);
            float inv  = rsqrtf(var + EPSV);
            float gm = gamma[f] * inv;
            sscale[f] = gm;
            sshift[f] = beta[f] - mean * gm;
        }
        __syncthreads();
    }

    if (mode == 0){
        const float* A = (const float*)Ain;
        #pragma unroll
        for (int rep = 0; rep < 8; rep++){
            int f  = rep * 256 + tid;
            int m  = f >> 5;
            int c4 = f & 31;
            int row = rowBase + m;
            if (row >= N_NODES) row = N_NODES - 1;
            float4 v = *(const float4*)(A + (size_t)row * D + c4 * 4);
            __half2 h0 = __floats2half2_rn(v.x, v.y);
            __half2 h1 = __floats2half2_rn(v.z, v.w);
            uint2 u; u.x = *(unsigned int*)&h0; u.y = *(unsigned int*)&h1;
            *(uint2*)&lds32[m * LSTR + 2 * c4] = u;
        }
    } else {
        const __half* A16 = (const __half*)Ain;
        #pragma unroll
        for (int rep = 0; rep < 4; rep++){
            int f  = rep * 256 + tid;
            int m  = f >> 4;
            int c8 = f & 15;
            int row = rowBase + m;
            if (row >= N_NODES) row = N_NODES - 1;
            uint4 v = *(const uint4*)(A16 + (size_t)row * D + c8 * 8);
            float4 sc0 = *(const float4*)&sscale[c8 * 8];
            float4 sc1 = *(const float4*)&sscale[c8 * 8 + 4];
            float4 sh0 = *(const float4*)&sshift[c8 * 8];
            float4 sh1 = *(const float4*)&sshift[c8 * 8 + 4];
            float2 f0 = __half22float2(*(__half2*)&v.x);
            float2 f1 = __half22float2(*(__half2*)&v.y);
            float2 f2 = __half22float2(*(__half2*)&v.z);
            float2 f3 = __half22float2(*(__half2*)&v.w);
            f0.x = relu_f(fmaf(f0.x, sc0.x, sh0.x));
            f0.y = relu_f(fmaf(f0.y, sc0.y, sh0.y));
            f1.x = relu_f(fmaf(f1.x, sc0.z, sh0.z));
            f1.y = relu_f(fmaf(f1.y, sc0.w, sh0.w));
            f2.x = relu_f(fmaf(f2.x, sc1.x, sh1.x));
            f2.y = relu_f(fmaf(f2.y, sc1.y, sh1.y));
            f3.x = relu_f(fmaf(f3.x, sc1.z, sh1.z));
            f3.y = relu_f(fmaf(f3.y, sc1.w, sh1.w));
            __half2 h0 = __floats2half2_rn(f0.x, f0.y);
            __half2 h1 = __floats2half2_rn(f1.x, f1.y);
            __half2 h2 = __floats2half2_rn(f2.x, f2.y);
            __half2 h3 = __floats2half2_rn(f3.x, f3.y);
            uint4 u;
            u.x = *(unsigned int*)&h0; u.y = *(unsigned int*)&h1;
            u.z = *(unsigned int*)&h2; u.w = *(unsigned int*)&h3;
            *(uint4*)&lds32[m * LSTR + 4 * c8] = u;
        }
    }
    {
        const uint4* gw = (const uint4*)wp;
        #pragma unroll
        for (int rep = 0; rep < 8; rep++){
            int f = rep * 256 + tid;
            int c = f >> 4;
            int q = f & 15;
            uint4 v = gw[f];
            *(uint4*)&lds32[WOFF + c * LSTR + 4 * q] = v;
        }
    }
    __syncthreads();

    int lane = tid & 63, wv = tid >> 6;
    int quad = lane >> 5;
    int ml   = (lane & 31) + (wv & 1) * 32;
    int cA   = (wv >> 1) * 64;
    int c0   = cA + (lane & 31);
    int c1   = c0 + 32;
    const unsigned int* aRow  = lds32 + ml * LSTR;
    const unsigned int* bRow0 = lds32 + WOFF + c0 * LSTR;
    const unsigned int* bRow1 = lds32 + WOFF + c1 * LSTR;
    floatx16 acc0 = {};
    floatx16 acc1 = {};
    #pragma unroll
    for (int ch = 0; ch < 8; ch++){
        int o = ch * 8 + quad * 4;
        half8 af = *(const half8*)(aRow  + o);
        half8 b0 = *(const half8*)(bRow0 + o);
        half8 b1 = *(const half8*)(bRow1 + o);
        acc0 = __builtin_amdgcn_mfma_f32_32x32x16_f16(af, b0, acc0, 0, 0, 0);
        acc1 = __builtin_amdgcn_mfma_f32_32x32x16_f16(af, b1, acc1, 0, 0, 0);
    }
    int rBase = rowBase + (wv & 1) * 32 + 4 * quad;
    #pragma unroll
    for (int r = 0; r < 16; r++){
        int outRow = rBase + (r & 3) + 8 * (r >> 2);
        if (outRow < N_NODES){
            float dv = dinv[outRow];
            outh[(size_t)outRow * D + c0] = __float2half(acc0[r] * dv);
            outh[(size_t)outRow * D + c1] = __float2half(acc1[r] * dv);
        }
    }
}

__device__ __forceinline__ void accum8(float* acc, uint4 v)
{
    float2 f0 = __half22float2(*(__half2*)&v.x);
    float2 f1 = __half22float2(*(__half2*)&v.y);
    float2 f2 = __half22float2(*(__half2*)&v.z);
    float2 f3 = __half22float2(*(__half2*)&v.w);
    acc[0] += f0.x; acc[1] += f0.y; acc[2] += f1.x; acc[3] += f1.y;
    acc[4] += f2.x; acc[5] += f2.y; acc[6] += f3.x; acc[7] += f3.y;
}

// ---------------- edge aggregation v6 (proven optimum; R5-exact) ---------------
// 16-lane groups, 16B/lane full-row gathers (256B rows, 100% line utilization),
// sequential 2 nodes/group, LDS stats epilogue, ONE coalesced 128-wide atomic
// set per block. Structural alternatives all measured worse:
//   per-wave scalar atomics (R4: 147us), dual-node interleave (R6: 50us, VGPR
//   36->56 occupancy loss), slice-partition w/ XCD affinity (R7: 92us, 4x line
//   waste + no affinity control), atomic CSR scatter (R8: 60us, line writeback
//   per atomic). DO NOT touch.
__global__ __launch_bounds__(256) void k_agg(const __half* __restrict__ t,
                                             const int* __restrict__ row_ptr,
                                             const int* __restrict__ csr_src,
                                             const float* __restrict__ dinv,
                                             const float* __restrict__ bias,
                                             __half* __restrict__ outb,
                                             float* __restrict__ Spart,
                                             float* __restrict__ Qpart)
{
    __shared__ float ldsS[4][128];
    __shared__ float ldsQ[4][128];
    int tid  = threadIdx.x;
    int lane = tid & 63;
    int wv   = tid >> 6;
    int q    = lane & 15;          // feature slot
    int g    = lane >> 4;          // group 0..3
    const uint4* t4 = (const uint4*)t;
    uint4* out4 = (uint4*)outb;

    float4 bia = ((const float4*)bias)[2 * q];
    float4 bib = ((const float4*)bias)[2 * q + 1];

    float sa[8] = {0.f,0.f,0.f,0.f,0.f,0.f,0.f,0.f};
    float qa[8] = {0.f,0.f,0.f,0.f,0.f,0.f,0.f,0.f};

    int i0 = blockIdx.x * 32 + wv * 8 + g * 2;   // group covers 2 nodes

    for (int n = 0; n < 2; n++){
        int i  = i0 + n;
        int p  = row_ptr[i];
        int pe = row_ptr[i + 1];
        float acc[8];
        {   // self row (pre-scaled by dinv[i] already)
            uint4 v = t4[(size_t)i * 16 + q];
            float2 f0 = __half22float2(*(__half2*)&v.x);
            float2 f1 = __half22float2(*(__half2*)&v.y);
            float2 f2 = __half22float2(*(__half2*)&v.z);
            float2 f3 = __half22float2(*(__half2*)&v.w);
            acc[0] = f0.x; acc[1] = f0.y; acc[2] = f1.x; acc[3] = f1.y;
            acc[4] = f2.x; acc[5] = f2.y; acc[6] = f3.x; acc[7] = f3.y;
        }
        for (; p + 4 <= pe; p += 4){
            int s0 = csr_src[p],     s1 = csr_src[p + 1];
            int s2 = csr_src[p + 2], s3 = csr_src[p + 3];
            uint4 v0 = t4[(size_t)s0 * 16 + q];
            uint4 v1 = t4[(size_t)s1 * 16 + q];
            uint4 v2 = t4[(size_t)s2 * 16 + q];
            uint4 v3 = t4[(size_t)s3 * 16 + q];
            accum8(acc, v0); accum8(acc, v1); accum8(acc, v2); accum8(acc, v3);
        }
        for (; p < pe; ++p){
            int s = csr_src[p];
            uint4 v = t4[(size_t)s * 16 + q];
            accum8(acc, v);
        }
        float dvi = dinv[i];
        acc[0] = fmaf(acc[0], dvi, bia.x);
        acc[1] = fmaf(acc[1], dvi, bia.y);
        acc[2] = fmaf(acc[2], dvi, bia.z);
        acc[3] = fmaf(acc[3], dvi, bia.w);
        acc[4] = fmaf(acc[4], dvi, bib.x);
        acc[5] = fmaf(acc[5], dvi, bib.y);
        acc[6] = fmaf(acc[6], dvi, bib.z);
        acc[7] = fmaf(acc[7], dvi, bib.w);
        __half2 o0 = __floats2half2_rn(acc[0], acc[1]);
        __half2 o1 = __floats2half2_rn(acc[2], acc[3]);
        __half2 o2 = __floats2half2_rn(acc[4], acc[5]);
        __half2 o3 = __floats2half2_rn(acc[6], acc[7]);
        uint4 ov;
        ov.x = *(unsigned int*)&o0; ov.y = *(unsigned int*)&o1;
        ov.z = *(unsigned int*)&o2; ov.w = *(unsigned int*)&o3;
        out4[(size_t)i * 16 + q] = ov;
        #pragma unroll
        for (int k = 0; k < 8; k++){
            sa[k] += acc[k];
            qa[k]  = fmaf(acc[k], acc[k], qa[k]);
        }
    }

    // combine the 4 groups' per-feature stats within the wave
    #pragma unroll
    for (int k = 0; k < 8; k++){
        sa[k] += __shfl_xor(sa[k], 16);
        sa[k] += __shfl_xor(sa[k], 32);
        qa[k] += __shfl_xor(qa[k], 16);
        qa[k] += __shfl_xor(qa[k], 32);
    }
    if (g == 0){
        #pragma unroll
        for (int k = 0; k < 8; k++){
            ldsS[wv][8 * q + k] = sa[k];
            ldsQ[wv][8 * q + k] = qa[k];
        }
    }
    __syncthreads();
    int slotBase = (blockIdx.x & (NSLOT - 1)) * 128;
    if (tid < 128){
        float s = ldsS[0][tid] + ldsS[1][tid] + ldsS[2][tid] + ldsS[3][tid];
        atomicAdd(&Spart[slotBase + tid], s);
    } else {
        int f = tid - 128;
        float qv = ldsQ[0][f] + ldsQ[1][f] + ldsQ[2][f] + ldsQ[3][f];
        atomicAdd(&Qpart[slotBase + f], qv);
    }
}

// ---------------- TAIL: fused fin2 + per-graph BN+ReLU+mean + MLP head --------
__global__ __launch_bounds__(256) void k_tail(const __half* __restrict__ h,
                                              const int* __restrict__ gstart,
                                              const float* __restrict__ Spart,
                                              const float* __restrict__ Qpart,
                                              const float* __restrict__ gamma,
                                              const float* __restrict__ beta,
                                              const float* __restrict__ W1,
                                              const float* __restrict__ b1,
                                              const float* __restrict__ W2,
                                              const float* __restrict__ b2,
                                              float* __restrict__ out)
{
    __shared__ float part[256];
    __shared__ float z[128];
    __shared__ float red[128];
    __shared__ float sscale[128];
    __shared__ float sshift[128];
    int g = blockIdx.x;
    int tid = threadIdx.x;
    int f = tid & 127;
    int hf = tid >> 7;                // 0/1: row-parity split

    {   // fused fin2
        const float* sp = (tid < 128) ? Spart : Qpart;
        float acc = 0.f;
        #pragma unroll 16
        for (int s = 0; s < NSLOT; s++)
            acc += sp[s * 128 + f];
        part[tid] = acc;
        __syncthreads();
        if (tid < 128){
            float Sv = part[f];
            float Qv = part[f + 128];
            float mean = Sv * (1.0f / N_NODES);
            float var  = fmaxf(Qv * (1.0f / N_NODES) - mean * mean, 0.0f);
            float inv  = rsqrtf(var + EPSV);
            float gm = gamma[f] * inv;
            sscale[f] = gm;
            sshift[f] = beta[f] - mean * gm;
        }
        __syncthreads();
    }

    int s0 = gstart[g], s1 = gstart[g + 1];
    float scv = sscale[f], shv = sshift[f];
    float acc = 0.f;
    for (int i = s0 + hf; i < s1; i += 2)
        acc += relu_f(fmaf(__half2float(h[(size_t)i * D + f]), scv, shv));
    part[tid] = acc;
    __syncthreads();
    if (tid < 128){
        float c = fmaxf((float)(s1 - s0), 1.0f);
        z[f] = (part[f] + part[f + 128]) / c;
    }
    __syncthreads();
    // head GEMV: thread (f,hf) covers k in [hf*64, hf*64+64)
    float a = 0.f;
    int k0 = hf * 64;
    #pragma unroll 8
    for (int k = k0; k < k0 + 64; k++)
        a = fmaf(z[k], W1[k * D + f], a);
    part[tid] = a;
    __syncthreads();
    if (tid < 128){
        float av = relu_f(part[f] + part[f + 128] + b1[f]);
        red[f] = av * W2[f];
    }
    __syncthreads();
    for (int s2 = 64; s2 > 0; s2 >>= 1){
        if (tid < s2) red[tid] += red[tid + s2];
        __syncthreads();
    }
    if (tid == 0) out[g] = red[0] + b2[0];
}

extern "C" void kernel_launch(void* const* d_in, const int* in_sizes, int n_in,
                              void* d_out, int out_size, void* d_ws, size_t ws_size,
                              hipStream_t stream)
{
    const float* x      = (const float*)d_in[0];
    const int*   ei     = (const int*)d_in[1];
    const int*   batch  = (const int*)d_in[2];
    const float* Ws     = (const float*)d_in[3];
    const float* bs     = (const float*)d_in[4];
    const float* gammas = (const float*)d_in[5];
    const float* betas  = (const float*)d_in[6];
    const float* W1     = (const float*)d_in[7];
    const float* b1     = (const float*)d_in[8];
    const float* W2     = (const float*)d_in[9];
    const float* b2     = (const float*)d_in[10];
    float* out = (float*)d_out;

    const int* src = ei;
    const int* dst = ei + N_EDGES;

    char* w = (char*)d_ws;
    size_t off = 0;
    auto alloc = [&](size_t bytes) -> void* {
        void* p = w + off;
        off += (bytes + 255) & ~(size_t)255;
        return p;
    };
    int*   row_ptr     = (int*)  alloc((size_t)(N_NODES + 1) * 4);
    float* dinv        = (float*)alloc((size_t)N_NODES * 4);
    int*   csr_src     = (int*)  alloc((size_t)N_EDGES * 4);
    int*   blockHist   = (int*)  alloc((size_t)NBLK * NBUK * 4);
    int*   colScan     = (int*)  alloc((size_t)NBLK * NBUK * 4);
    int*   bucketTotal = (int*)  alloc((size_t)NBUK * 4);
    unsigned int* wpack = (unsigned int*)alloc((size_t)3 * 128 * 64 * 4);
    int*   gstart      = (int*)  alloc((size_t)(N_GRAPHS + 1) * 4);
    size_t zoff = off;                       // --- zero-span start ---
    float* stats       = (float*)alloc((size_t)3 * 2 * NSLOT * 128 * 4); // per layer: Spart, Qpart
    size_t zend = off;                       // --- zero-span end ---
    __half* tbuf       = (__half*)alloc((size_t)N_NODES * 128 * 2);  // fp16 gather table (dinv-scaled)
    __half* hbuf       = (__half*)alloc((size_t)N_NODES * 128 * 2);  // fp16 h (pre-BN)
    if (off > ws_size) return;

    // alias scratch (consumed before tbuf is first written; stream-ordered)
    int2* ebuf = (int2*)tbuf;    // 6.4 MB < 25.6 MB

    k_front<<<NBLK + 96, 256, 0, stream>>>(dst, blockHist, Ws, wpack,
                                           (unsigned int*)(w + zoff),
                                           (int)((zend - zoff) >> 2),
                                           batch, gstart, row_ptr);
    k_p2a<<<NBUK, 256, 0, stream>>>(blockHist, colScan, bucketTotal);
    k_p3 <<<NBLK, 256, 0, stream>>>(src, dst, colScan, bucketTotal, ebuf);
    k_p4 <<<NBUK, 256, 0, stream>>>(ebuf, bucketTotal, row_ptr, csr_src, dinv);

    const void* curIn = (const void*)x;
    for (int l = 0; l < 3; l++){
        float* Sp = stats + (size_t)l * 2 * NSLOT * 128;
        float* Qp = Sp + NSLOT * 128;
        float* Spm = stats + (size_t)(l - 1) * 2 * NSLOT * 128;   // prev layer (l>=1)
        float* Qpm = Spm + NSLOT * 128;
        k_gemm<<<(N_NODES + 63) / 64, 256, 0, stream>>>(
            curIn, wpack + l * 8192,
            l ? Spm : nullptr,
            l ? Qpm : nullptr,
            l ? gammas + (l - 1) * 128 : nullptr,
            l ? betas  + (l - 1) * 128 : nullptr,
            dinv, tbuf, l ? 1 : 0);
        k_agg<<<N_NODES / 32, 256, 0, stream>>>(
            tbuf, row_ptr, csr_src, dinv,
            bs + l * 128, hbuf, Sp, Qp);
        curIn = (const void*)hbuf;
    }

    {
        float* Sp2 = stats + (size_t)2 * 2 * NSLOT * 128;
        float* Qp2 = Sp2 + NSLOT * 128;
        k_tail<<<N_GRAPHS, 256, 0, stream>>>(hbuf, gstart,
                                             Sp2, Qp2,
                                             gammas + 2 * 128, betas + 2 * 128,
                                             W1, b1, W2, b2, out);
    }
}